// Round 19
// baseline (46.704 us; speedup 1.0000x reference)
//
#include <hip/hip_runtime.h>
#include <hip/hip_bf16.h>
#include <math.h>

#define D_DIM 128
#define R_DIM 64
#define T_DIM 2048
#define B_DIM 8
#define NS 4                       // split-K factor over the s dimension
#define SCHUNK (T_DIM / NS)        // 512
#define SBLK 32                    // s-tile per iteration
#define NIT (SCHUNK / SBLK)        // 16
#define KE_CONST (0.08838834764831845f * 1.4426950408889634f)  // 1/sqrt(128) * log2(e)

typedef __attribute__((ext_vector_type(8))) short bf16x8;
typedef __attribute__((ext_vector_type(4))) short s16x4;
typedef __attribute__((ext_vector_type(4))) float f32x4;
typedef __attribute__((ext_vector_type(16))) float f32x16;

__device__ inline unsigned short f2bf(float f) {
  union { float f; unsigned int u; } v; v.f = f;
  return (unsigned short)((v.u + 0x7FFFu + ((v.u >> 16) & 1u)) >> 16);
}
__device__ inline float bf2f(unsigned short u) {
  union { unsigned int u; float f; } v; v.u = ((unsigned int)u) << 16;
  return v.f;
}
// packed RNE f32->bf16 pair: low half = lo, high half = hi (T12 recipe)
__device__ inline unsigned int cvt_pk_bf16(float lo, float hi) {
  unsigned int r;
  asm("v_cvt_pk_bf16_f32 %0, %1, %2" : "=v"(r) : "v"(lo), "v"(hi));
  return r;
}
// v_permlane32_swap_b32: lane l<32: a'=a, b'=a[l+32]; lane l>=32: a'=b[l-32], b'=b.
__device__ inline void permswap(unsigned int& a, unsigned int& b) {
  asm("v_permlane32_swap_b32 %0, %1" : "+v"(a), "+v"(b));
}
// raw 2^x (input |x| small -> no libm edge handling needed)
__device__ inline float fexp2(float x) {
  float r;
  asm("v_exp_f32 %0, %1" : "=v"(r) : "v"(x));
  return r;
}

// async global->LDS, 16B per lane; LDS dest = wave-uniform base + lane*16
__device__ inline void async16(const short* l, const unsigned short* g) {
  __builtin_amdgcn_global_load_lds(
      (const __attribute__((address_space(1))) unsigned int*)g,
      (__attribute__((address_space(3))) unsigned int*)l, 16, 0, 0);
}

// ---------------- Kernel A: S = W W^T / sqrt(D*R), bf16, FRAGMENT layout ----------------
// Layout matches k_prep's B-frag read: Sb[((dc*4+kc)*64 + lane)*8 + j] with
// lane = g*16+c holding S[dc*16+c][kc*32+g*8+j].  (R12-verified)
__global__ void k_s(const float* __restrict__ W, unsigned short* __restrict__ Sb) {
  int gid = blockIdx.x * 256 + threadIdx.x;
  int i = gid >> 7, j = gid & 127;
  const float* wi = W + i * R_DIM;
  const float* wj = W + j * R_DIM;
  float acc = 0.f;
#pragma unroll 8
  for (int r = 0; r < R_DIM; ++r) acc += wi[r] * wj[r];
  int off = (((i >> 4) * 4 + (j >> 5)) * 64 + ((j & 31) >> 3) * 16 + (i & 15)) * 8 + (j & 7);
  Sb[off] = f2bf(acc * 0.011048543456039806f);  // 1/sqrt(128*64)
}

// ---------------- Kernel B: MFMA Q = X*S, outputs in k_attn frag layout ----------------
// Qb frag layout (R12-verified):
// Qb[((b*64 + t/32)*8 + dc)*512 + ((d>>3 & 1)*32 + (t&31))*8 + (d&7)], d = dc*16 + c.
__global__ void __launch_bounds__(128) k_prep(
    const float* __restrict__ X, const unsigned short* __restrict__ Sb,
    unsigned short* __restrict__ Qb, unsigned short* __restrict__ Xb,
    unsigned short* __restrict__ Xt, float* __restrict__ part) {
  const int tid = threadIdx.x;
  const int w = tid >> 6, lane = tid & 63;
  const int g = lane >> 4, c = lane & 15;
  const int b = blockIdx.y;
  const int t0 = blockIdx.x * 32;
  const int tw = t0 + w * 16;           // this wave's 16 rows

  __shared__ __align__(16) short xbT[D_DIM * 32];   // [e][t-local], 8 KB
  __shared__ float red[2];

  // load X rows, cvt to bf16 frags, write Xb, fill xbT transpose
  union FU { unsigned int wd[4]; bf16x8 v; };
  bf16x8 xf[4];
#pragma unroll
  for (int kc = 0; kc < 4; ++kc) {
    const float* xp = X + ((size_t)(b * T_DIM + tw + c)) * D_DIM + kc * 32 + g * 8;
    f32x4 a = *(const f32x4*)xp;
    f32x4 bb = *(const f32x4*)(xp + 4);
    FU f;
    f.wd[0] = cvt_pk_bf16(a[0], a[1]);
    f.wd[1] = cvt_pk_bf16(a[2], a[3]);
    f.wd[2] = cvt_pk_bf16(bb[0], bb[1]);
    f.wd[3] = cvt_pk_bf16(bb[2], bb[3]);
    xf[kc] = f.v;
    *(bf16x8*)(Xb + ((size_t)(b * T_DIM + tw + c)) * D_DIM + kc * 32 + g * 8) = f.v;
#pragma unroll
    for (int jw = 0; jw < 4; ++jw) {
      unsigned int wv = f.wd[jw];
      int e = kc * 32 + g * 8 + jw * 2;
      xbT[(e + 0) * 32 + w * 16 + c] = (short)wv;
      xbT[(e + 1) * 32 + w * 16 + c] = (short)(wv >> 16);
    }
  }

  // MFMA: acc[dc] = X(16 rows) * S, B-frags COALESCED from frag-layout Sb (L2-hot)
  f32x4 acc[8];
#pragma unroll
  for (int dc = 0; dc < 8; ++dc) acc[dc] = (f32x4){0.f, 0.f, 0.f, 0.f};
#pragma unroll
  for (int dc = 0; dc < 8; ++dc) {
    bf16x8 sf[4];
#pragma unroll
    for (int kc = 0; kc < 4; ++kc)
      sf[kc] = *(const bf16x8*)(Sb + ((size_t)(dc * 4 + kc) * 64 + lane) * 8);
#pragma unroll
    for (int kc = 0; kc < 4; ++kc)
      acc[dc] = __builtin_amdgcn_mfma_f32_16x16x32_bf16(xf[kc], sf[kc], acc[dc], 0, 0, 0);
  }

  __syncthreads();   // xbT complete (both waves)

  // trace partial (unscaled) + store Q pre-scaled by KE as bf16 in attn-frag layout
  float trp = 0.f;
#pragma unroll
  for (int dc = 0; dc < 8; ++dc)
#pragma unroll
    for (int r = 0; r < 4; ++r) {
      float q = acc[dc][r];
      float x = bf2f((unsigned short)xbT[(dc * 16 + c) * 32 + w * 16 + g * 4 + r]);
      trp += q * x;
      int t = tw + g * 4 + r;
      size_t qoff = (((size_t)(b * 64 + (t >> 5)) * 8 + dc) * 512 +
                     ((c >> 3) * 32 + (t & 31)) * 8 + (c & 7));
      Qb[qoff] = (unsigned short)cvt_pk_bf16(q * KE_CONST, 0.f);
    }

  // write Xt from xbT: 4 passes x 32 rows, b128 in / b128 out
#pragma unroll
  for (int p = 0; p < 4; ++p) {
    int row = p * 32 + (tid >> 2);
    bf16x8 v = *(const bf16x8*)&xbT[row * 32 + (tid & 3) * 8];
    *(bf16x8*)(Xt + ((size_t)(b * D_DIM + row)) * T_DIM + t0 + (tid & 3) * 8) = v;
  }

  // reduce trace partial: wave shuffle -> cross-wave via LDS
  trp += __shfl_xor(trp, 1); trp += __shfl_xor(trp, 2);
  trp += __shfl_xor(trp, 4); trp += __shfl_xor(trp, 8);
  trp += __shfl_xor(trp, 16); trp += __shfl_xor(trp, 32);
  if (lane == 0) red[w] = trp;
  __syncthreads();
  if (tid == 0) part[b * 64 + blockIdx.x] = red[0] + red[1];
}

// ---------------- Kernel C: flash attention — R17 schedule, 2-wave blocks ----------------
// R19: blocks halved to 2 waves (64 t-rows), grid 1024 = 4 independent
// barrier-groups/CU (was 2). Same total waves; when one block stalls at its
// staging barrier, 3 others at uncorrelated phases keep the pipes fed.
// Staging: 8 issues/lane/iter, counted s_waitcnt vmcnt(8). Inner loop
// byte-identical to R17 (split QK chains, hoisted diag, raw v_exp_f32).
__global__ void __launch_bounds__(128, 2) k_attn(
    const unsigned short* __restrict__ Qb, const unsigned short* __restrict__ Xb,
    const unsigned short* __restrict__ Xt, const float* __restrict__ part,
    unsigned short* __restrict__ accp, float* __restrict__ rsp) {
  const int tid = threadIdx.x;
  const int wave = tid >> 6, lane = tid & 63;
  const int tl = lane & 31;      // C/D col = t-local; A row = s-local
  const int h = lane >> 5;       // half-wave -> k_local*8
  // XCD-aware decomposition: bid&7 == b pins batch b's working set to one XCD.
  const int lin = blockIdx.x;
  const int b = lin & 7;
  const int kk = lin >> 3;
  const int ns = kk & 3;
  const int tile = kk >> 2;                      // 0..31
  const int t0w = tile * 64 + wave * 32;         // 32 q-rows per wave

  const unsigned short* Xbb = Xb + (size_t)b * T_DIM * D_DIM;
  const unsigned short* Xtb = Xt + (size_t)b * D_DIM * T_DIM;

  // inline trace reduction (per-wave redundant, L2-hot)
  float tv = part[b * 64 + lane];
  tv += __shfl_xor(tv, 1); tv += __shfl_xor(tv, 2);
  tv += __shfl_xor(tv, 4); tv += __shfl_xor(tv, 8);
  tv += __shfl_xor(tv, 16); tv += __shfl_xor(tv, 32);
  const float ctrK = tv * (1.0f / T_DIM) * KE_CONST;
  const float expCtr = fexp2(-ctrK);   // diag correction as multiplier

  __shared__ __align__(16) short sKs[2][SBLK * D_DIM];   // 2 x 8 KB
  __shared__ __align__(16) short sVs[2][D_DIM * SBLK];   // 2 x 8 KB

  // swizzled ds_read offsets (shorts) — R11-verified
  int oK[8], oV[4][2];
#pragma unroll
  for (int kc = 0; kc < 8; ++kc)
    oK[kc] = tl * 128 + (((kc * 2 + h) ^ (tl & 15)) * 8);
#pragma unroll
  for (int dt = 0; dt < 4; ++dt)
#pragma unroll
    for (int sck = 0; sck < 2; ++sck)
      oV[dt][sck] = (dt * 32 + tl) * 32 + (((sck * 2 + h) ^ (tl & 3)) * 8);

  // Q B-frags, COALESCED from frag-layout Qb (t0w>>5 == tile*2 + wave)
  const unsigned short* qbase =
      Qb + ((size_t)(b * 64 + tile * 2 + wave)) * 8 * 512;
  bf16x8 qf[8];
#pragma unroll
  for (int kc = 0; kc < 8; ++kc)
    qf[kc] = *(const bf16x8*)(qbase + (size_t)kc * 512 + lane * 8);

  f32x16 acc[4];
#pragma unroll
  for (int dt = 0; dt < 4; ++dt)
#pragma unroll
    for (int r = 0; r < 16; ++r) acc[dt][r] = 0.f;
  float denacc = 0.f;

  const int s_beg = ns * SCHUNK;

  // staging: 1024 16B chunks over 2 waves (4 K-issues + 4 V-issues per lane = 8 vmem)
  auto stage = [&](int buf, int sb) {
#pragma unroll
    for (int q = 0; q < 4; ++q) {
      int j = wave * 256 + q * 64 + lane;
      int row = j >> 4, sc = j & 15;
      int lc = sc ^ (row & 15);
      async16(&sKs[buf][(wave * 256 + q * 64) * 8],
              Xbb + (size_t)(sb + row) * D_DIM + lc * 8);
    }
#pragma unroll
    for (int q = 0; q < 4; ++q) {
      int j = wave * 256 + q * 64 + lane;
      int row = j >> 2, sc = j & 3;
      int lc = sc ^ (row & 3);
      async16(&sVs[buf][(wave * 256 + q * 64) * 8],
              Xtb + (size_t)row * T_DIM + sb + lc * 8);
    }
  };

  stage(0, s_beg);

  for (int it = 0; it < NIT; ++it) {
    const int buf = it & 1;
    const int sb = s_beg + it * SBLK;

    // issue next tile, then counted wait: own prior-tile (buf) issues complete,
    // the 8 just-issued (buf^1) stay in flight across the barrier.
    if (it < NIT - 1) {
      stage(buf ^ 1, sb + SBLK);
      asm volatile("s_waitcnt vmcnt(8)" ::: "memory");
    } else {
      asm volatile("s_waitcnt vmcnt(0)" ::: "memory");
    }
    __builtin_amdgcn_sched_barrier(0);
    __builtin_amdgcn_s_barrier();        // both waves: buf fully staged

    const short* kb = &sKs[buf][0];
    const short* vb = &sVs[buf][0];

    // LDS -> reg fragments (compiler inserts lgkmcnt before MFMA use)
    bf16x8 kf[8];
#pragma unroll
    for (int kc = 0; kc < 8; ++kc)
      kf[kc] = *(const bf16x8*)(kb + oK[kc]);
    bf16x8 vf[4][2];
#pragma unroll
    for (int dt = 0; dt < 4; ++dt)
#pragma unroll
      for (int sck = 0; sck < 2; ++sck)
        vf[dt][sck] = *(const bf16x8*)(vb + oV[dt][sck]);

    // ---- QK^T (swapped), TWO independent 4-deep chains -> merge ----
    f32x16 sa, sb2;
#pragma unroll
    for (int r = 0; r < 16; ++r) { sa[r] = 0.f; sb2[r] = 0.f; }
#pragma unroll
    for (int kc = 0; kc < 4; ++kc) {
      sa  = __builtin_amdgcn_mfma_f32_32x32x16_bf16(kf[kc],     qf[kc],     sa,  0, 0, 0);
      sb2 = __builtin_amdgcn_mfma_f32_32x32x16_bf16(kf[kc + 4], qf[kc + 4], sb2, 0, 0, 0);
    }
    f32x16 sc = sa + sb2;

    const bool isd = (sb == t0w);   // wave-uniform; both 32-aligned

    // ---- per s-chunk of 16: exp2 + in-register pack -> PV (R10-verified) ----
#pragma unroll
    for (int sck = 0; sck < 2; ++sck) {
      float p[8];
#pragma unroll
      for (int q = 0; q < 8; ++q) p[q] = fexp2(sc[sck * 8 + q]);
      if (isd) {   // wave-uniform branch: only the diagonal iteration
#pragma unroll
        for (int q = 0; q < 8; ++q) {
          int rowid = (q & 3) + 8 * (q >> 2) + 16 * sck + 4 * h;  // s_local
          if (rowid == tl) p[q] *= expCtr;
        }
      }
#pragma unroll
      for (int q = 0; q < 8; ++q) denacc += p[q];
      unsigned int W0 = cvt_pk_bf16(p[0], p[1]);
      unsigned int W1 = cvt_pk_bf16(p[2], p[3]);
      unsigned int W2 = cvt_pk_bf16(p[4], p[5]);
      unsigned int W3 = cvt_pk_bf16(p[6], p[7]);
      permswap(W0, W2);
      permswap(W1, W3);
      union PU { unsigned int wd[4]; bf16x8 v; } pu;
      pu.wd[0] = W0; pu.wd[1] = W1; pu.wd[2] = W2; pu.wd[3] = W3;
#pragma unroll
      for (int dt = 0; dt < 4; ++dt)
        acc[dt] = __builtin_amdgcn_mfma_f32_32x32x16_bf16(pu.v, vf[dt][sck],
                                                          acc[dt], 0, 0, 0);
    }

    // both waves done reading buf before anyone re-stages it next iteration
    __builtin_amdgcn_s_barrier();
  }

  // ---- den: own half + other half (same t, lane^32) ----
  float den = denacc + __shfl_xor(denacc, 32);
  if (lane < 32)
    rsp[(b * NS + ns) * T_DIM + t0w + lane] = den;

  // ---- write num partials (bf16), 32x32 C/D layout (R10-verified) ----
  const size_t pbase = ((size_t)(b * NS + ns)) * T_DIM * D_DIM;
#pragma unroll
  for (int dt = 0; dt < 4; ++dt)
#pragma unroll
    for (int r = 0; r < 16; ++r) {
      int rowid = (r & 3) + 8 * (r >> 2) + 4 * h;   // t_local
      accp[pbase + (size_t)(t0w + rowid) * D_DIM + dt * 32 + tl] =
          (unsigned short)cvt_pk_bf16(acc[dt][r], 0.f);
    }
}

// ---------------- Kernel D: combine split-K partials, 8 elems/thread, b128 ----------------
// XCD swizzle: bid&7 == b so accp/rsp reads hit the XCD-local L2.
__global__ void __launch_bounds__(256) k_comb(
    const unsigned short* __restrict__ accp, const float* __restrict__ rsp,
    float* __restrict__ out) {
  const int lin = blockIdx.x;
  const int b = lin & 7;
  const int kk = lin >> 3;                      // 0..127
  int ib = kk * 2048 + threadIdx.x * 8;         // element base within batch
  int d = ib & 127;
  int t = ib >> 7;
  float num[8] = {0.f, 0.f, 0.f, 0.f, 0.f, 0.f, 0.f, 0.f};
  float den = 0.f;
#pragma unroll
  for (int ns = 0; ns < NS; ++ns) {
    const unsigned short* p =
        accp + (((size_t)(b * NS + ns)) * T_DIM + t) * D_DIM + d;
    bf16x8 v = *(const bf16x8*)p;
#pragma unroll
    for (int j = 0; j < 8; ++j) num[j] += bf2f((unsigned short)v[j]);
    den += rsp[(b * NS + ns) * T_DIM + t];
  }
  float inv = 1.0f / den;
  float* o = out + ((size_t)b * T_DIM * D_DIM + ib);
  f32x4 o0 = (f32x4){num[0] * inv, num[1] * inv, num[2] * inv, num[3] * inv};
  f32x4 o1 = (f32x4){num[4] * inv, num[5] * inv, num[6] * inv, num[7] * inv};
  *(f32x4*)(o + 0) = o0;
  *(f32x4*)(o + 4) = o1;
}

extern "C" void kernel_launch(void* const* d_in, const int* in_sizes, int n_in,
                              void* d_out, int out_size, void* d_ws, size_t ws_size,
                              hipStream_t stream) {
  const float* X = (const float*)d_in[0];  // (8, 2048, 128) fp32
  const float* W = (const float*)d_in[1];  // (128, 64) fp32
  float* out = (float*)d_out;
  char* ws = (char*)d_ws;

  unsigned short* Sb = (unsigned short*)(ws);                 // 32 KB bf16 (frag layout)
  float* part        = (float*)(ws + 32768);                  // 2 KB
  unsigned short* Qb = (unsigned short*)(ws + 65536);         // 4 MB bf16 (frag layout)
  unsigned short* Xb = (unsigned short*)(ws + 65536 + 4194304);              // 4 MB
  unsigned short* Xt = (unsigned short*)(ws + 65536 + 2 * 4194304);          // 4 MB
  unsigned short* accp = (unsigned short*)(ws + 65536 + 3 * 4194304);        // 16 MB
  float* rsp         = (float*)(ws + 65536 + 3 * 4194304 + 16777216);        // 256 KB
  // total ws use: ~28.9 MB

  k_s<<<64, 256, 0, stream>>>(W, Sb);
  k_prep<<<dim3(T_DIM / 32, B_DIM), 128, 0, stream>>>(X, Sb, Qb, Xb, Xt, part);
  k_attn<<<(T_DIM / 64) * NS * B_DIM, 128, 0, stream>>>(Qb, Xb, Xt, part, accp, rsp);
  k_comb<<<B_DIM * 128, 256, 0, stream>>>(accp, rsp, out);
}

// Round 20
// 43.737 us; speedup vs baseline: 1.0678x; 1.0678x over previous
//
#include <hip/hip_runtime.h>
#include <hip/hip_bf16.h>
#include <math.h>

#define D_DIM 128
#define R_DIM 64
#define T_DIM 2048
#define B_DIM 8
#define NS 4                       // split-K factor over the s dimension
#define SCHUNK (T_DIM / NS)        // 512
#define SBLK 64                    // s-tile per staged iteration (R20: 32 -> 64)
#define NIT (SCHUNK / SBLK)        // 8
#define KE_CONST (0.08838834764831845f * 1.4426950408889634f)  // 1/sqrt(128) * log2(e)

typedef __attribute__((ext_vector_type(8))) short bf16x8;
typedef __attribute__((ext_vector_type(4))) short s16x4;
typedef __attribute__((ext_vector_type(4))) float f32x4;
typedef __attribute__((ext_vector_type(16))) float f32x16;

__device__ inline unsigned short f2bf(float f) {
  union { float f; unsigned int u; } v; v.f = f;
  return (unsigned short)((v.u + 0x7FFFu + ((v.u >> 16) & 1u)) >> 16);
}
__device__ inline float bf2f(unsigned short u) {
  union { unsigned int u; float f; } v; v.u = ((unsigned int)u) << 16;
  return v.f;
}
// packed RNE f32->bf16 pair: low half = lo, high half = hi (T12 recipe)
__device__ inline unsigned int cvt_pk_bf16(float lo, float hi) {
  unsigned int r;
  asm("v_cvt_pk_bf16_f32 %0, %1, %2" : "=v"(r) : "v"(lo), "v"(hi));
  return r;
}
// v_permlane32_swap_b32: lane l<32: a'=a, b'=a[l+32]; lane l>=32: a'=b[l-32], b'=b.
__device__ inline void permswap(unsigned int& a, unsigned int& b) {
  asm("v_permlane32_swap_b32 %0, %1" : "+v"(a), "+v"(b));
}
// raw 2^x (input |x| small -> no libm edge handling needed)
__device__ inline float fexp2(float x) {
  float r;
  asm("v_exp_f32 %0, %1" : "=v"(r) : "v"(x));
  return r;
}

// async global->LDS, 16B per lane; LDS dest = wave-uniform base + lane*16
__device__ inline void async16(const short* l, const unsigned short* g) {
  __builtin_amdgcn_global_load_lds(
      (const __attribute__((address_space(1))) unsigned int*)g,
      (__attribute__((address_space(3))) unsigned int*)l, 16, 0, 0);
}

// ---------------- Kernel A: S = W W^T / sqrt(D*R), bf16, FRAGMENT layout ----------------
// Layout matches k_prep's B-frag read: Sb[((dc*4+kc)*64 + lane)*8 + j] with
// lane = g*16+c holding S[dc*16+c][kc*32+g*8+j].  (R12-verified)
__global__ void k_s(const float* __restrict__ W, unsigned short* __restrict__ Sb) {
  int gid = blockIdx.x * 256 + threadIdx.x;
  int i = gid >> 7, j = gid & 127;
  const float* wi = W + i * R_DIM;
  const float* wj = W + j * R_DIM;
  float acc = 0.f;
#pragma unroll 8
  for (int r = 0; r < R_DIM; ++r) acc += wi[r] * wj[r];
  int off = (((i >> 4) * 4 + (j >> 5)) * 64 + ((j & 31) >> 3) * 16 + (i & 15)) * 8 + (j & 7);
  Sb[off] = f2bf(acc * 0.011048543456039806f);  // 1/sqrt(128*64)
}

// ---------------- Kernel B: MFMA Q = X*S, outputs in k_attn frag layout ----------------
// Qb frag layout (R12-verified):
// Qb[((b*64 + t/32)*8 + dc)*512 + ((d>>3 & 1)*32 + (t&31))*8 + (d&7)], d = dc*16 + c.
__global__ void __launch_bounds__(128) k_prep(
    const float* __restrict__ X, const unsigned short* __restrict__ Sb,
    unsigned short* __restrict__ Qb, unsigned short* __restrict__ Xb,
    unsigned short* __restrict__ Xt, float* __restrict__ part) {
  const int tid = threadIdx.x;
  const int w = tid >> 6, lane = tid & 63;
  const int g = lane >> 4, c = lane & 15;
  const int b = blockIdx.y;
  const int t0 = blockIdx.x * 32;
  const int tw = t0 + w * 16;           // this wave's 16 rows

  __shared__ __align__(16) short xbT[D_DIM * 32];   // [e][t-local], 8 KB
  __shared__ float red[2];

  // load X rows, cvt to bf16 frags, write Xb, fill xbT transpose
  union FU { unsigned int wd[4]; bf16x8 v; };
  bf16x8 xf[4];
#pragma unroll
  for (int kc = 0; kc < 4; ++kc) {
    const float* xp = X + ((size_t)(b * T_DIM + tw + c)) * D_DIM + kc * 32 + g * 8;
    f32x4 a = *(const f32x4*)xp;
    f32x4 bb = *(const f32x4*)(xp + 4);
    FU f;
    f.wd[0] = cvt_pk_bf16(a[0], a[1]);
    f.wd[1] = cvt_pk_bf16(a[2], a[3]);
    f.wd[2] = cvt_pk_bf16(bb[0], bb[1]);
    f.wd[3] = cvt_pk_bf16(bb[2], bb[3]);
    xf[kc] = f.v;
    *(bf16x8*)(Xb + ((size_t)(b * T_DIM + tw + c)) * D_DIM + kc * 32 + g * 8) = f.v;
#pragma unroll
    for (int jw = 0; jw < 4; ++jw) {
      unsigned int wv = f.wd[jw];
      int e = kc * 32 + g * 8 + jw * 2;
      xbT[(e + 0) * 32 + w * 16 + c] = (short)wv;
      xbT[(e + 1) * 32 + w * 16 + c] = (short)(wv >> 16);
    }
  }

  // MFMA: acc[dc] = X(16 rows) * S, B-frags COALESCED from frag-layout Sb (L2-hot)
  f32x4 acc[8];
#pragma unroll
  for (int dc = 0; dc < 8; ++dc) acc[dc] = (f32x4){0.f, 0.f, 0.f, 0.f};
#pragma unroll
  for (int dc = 0; dc < 8; ++dc) {
    bf16x8 sf[4];
#pragma unroll
    for (int kc = 0; kc < 4; ++kc)
      sf[kc] = *(const bf16x8*)(Sb + ((size_t)(dc * 4 + kc) * 64 + lane) * 8);
#pragma unroll
    for (int kc = 0; kc < 4; ++kc)
      acc[dc] = __builtin_amdgcn_mfma_f32_16x16x32_bf16(xf[kc], sf[kc], acc[dc], 0, 0, 0);
  }

  __syncthreads();   // xbT complete (both waves)

  // trace partial (unscaled) + store Q pre-scaled by KE as bf16 in attn-frag layout
  float trp = 0.f;
#pragma unroll
  for (int dc = 0; dc < 8; ++dc)
#pragma unroll
    for (int r = 0; r < 4; ++r) {
      float q = acc[dc][r];
      float x = bf2f((unsigned short)xbT[(dc * 16 + c) * 32 + w * 16 + g * 4 + r]);
      trp += q * x;
      int t = tw + g * 4 + r;
      size_t qoff = (((size_t)(b * 64 + (t >> 5)) * 8 + dc) * 512 +
                     ((c >> 3) * 32 + (t & 31)) * 8 + (c & 7));
      Qb[qoff] = (unsigned short)cvt_pk_bf16(q * KE_CONST, 0.f);
    }

  // write Xt from xbT: 4 passes x 32 rows, b128 in / b128 out
#pragma unroll
  for (int p = 0; p < 4; ++p) {
    int row = p * 32 + (tid >> 2);
    bf16x8 v = *(const bf16x8*)&xbT[row * 32 + (tid & 3) * 8];
    *(bf16x8*)(Xt + ((size_t)(b * D_DIM + row)) * T_DIM + t0 + (tid & 3) * 8) = v;
  }

  // reduce trace partial: wave shuffle -> cross-wave via LDS
  trp += __shfl_xor(trp, 1); trp += __shfl_xor(trp, 2);
  trp += __shfl_xor(trp, 4); trp += __shfl_xor(trp, 8);
  trp += __shfl_xor(trp, 16); trp += __shfl_xor(trp, 32);
  if (lane == 0) red[w] = trp;
  __syncthreads();
  if (tid == 0) part[b * 64 + blockIdx.x] = red[0] + red[1];
}

// ---------------- Kernel C: flash attention — R17 geometry, SBLK=64 ----------------
// 4 waves x 32 t-rows, 512 blocks (2 blocks/CU). R20: 64-s staged tiles ->
// barriers per block lifetime halved (8 staged tiles, 2 barriers each) and the
// V tile ([128][64], 8 chunk-slots/row) gets full 8-slot XOR spread (~4-way
// conflicts vs ~8 before). Two 32-s sub-iterations per staged tile, each
// byte-equivalent to R17's inner iteration. Counted s_waitcnt vmcnt(8).
__global__ void __launch_bounds__(256, 2) k_attn(
    const unsigned short* __restrict__ Qb, const unsigned short* __restrict__ Xb,
    const unsigned short* __restrict__ Xt, const float* __restrict__ part,
    unsigned short* __restrict__ accp, float* __restrict__ rsp) {
  const int tid = threadIdx.x;
  const int wave = tid >> 6, lane = tid & 63;
  const int tl = lane & 31;      // C/D col = t-local; A row = s-local
  const int h = lane >> 5;       // half-wave -> k_local*8
  // XCD-aware decomposition: bid&7 == b pins batch b's working set to one XCD.
  const int lin = blockIdx.x;
  const int b = lin & 7;
  const int kk = lin >> 3;
  const int ns = kk & 3;
  const int tile = kk >> 2;                      // 0..15
  const int t0w = tile * 128 + wave * 32;        // 32 q-rows per wave

  const unsigned short* Xbb = Xb + (size_t)b * T_DIM * D_DIM;
  const unsigned short* Xtb = Xt + (size_t)b * D_DIM * T_DIM;

  // inline trace reduction (per-wave redundant, L2-hot)
  float tv = part[b * 64 + lane];
  tv += __shfl_xor(tv, 1); tv += __shfl_xor(tv, 2);
  tv += __shfl_xor(tv, 4); tv += __shfl_xor(tv, 8);
  tv += __shfl_xor(tv, 16); tv += __shfl_xor(tv, 32);
  const float ctrK = tv * (1.0f / T_DIM) * KE_CONST;
  const float expCtr = fexp2(-ctrK);   // diag correction as multiplier

  __shared__ __align__(16) short sKs[2][SBLK * D_DIM];   // 2 x 16 KB
  __shared__ __align__(16) short sVs[2][D_DIM * SBLK];   // 2 x 16 KB

  // swizzled ds_read offsets (shorts)
  int oK[8];                    // K: row tl (+sub*32 added at use), 16-slot XOR
#pragma unroll
  for (int kc = 0; kc < 8; ++kc)
    oK[kc] = tl * 128 + (((kc * 2 + h) ^ (tl & 15)) * 8);
  // V: [128][64] rows, chunk index (sub*4 + sck*2 + h) ^ (tl&7), 8-slot XOR

  // Q B-frags, COALESCED from frag-layout Qb (R12-verified layout)
  const unsigned short* qbase =
      Qb + ((size_t)(b * 64 + tile * 4 + wave)) * 8 * 512;
  bf16x8 qf[8];
#pragma unroll
  for (int kc = 0; kc < 8; ++kc)
    qf[kc] = *(const bf16x8*)(qbase + (size_t)kc * 512 + lane * 8);

  f32x16 acc[4];
#pragma unroll
  for (int dt = 0; dt < 4; ++dt)
#pragma unroll
    for (int r = 0; r < 16; ++r) acc[dt][r] = 0.f;
  float denacc = 0.f;

  const int s_beg = ns * SCHUNK;

  // staging: K 1024 chunks + V 1024 chunks over 4 waves (4+4 issues/lane = 8 vmem)
  auto stage = [&](int buf, int sb) {
#pragma unroll
    for (int q = 0; q < 4; ++q) {
      int j = wave * 256 + q * 64 + lane;
      int row = j >> 4, sc = j & 15;          // 64 rows x 16 chunks
      int lc = sc ^ (row & 15);
      async16(&sKs[buf][(wave * 256 + q * 64) * 8],
              Xbb + (size_t)(sb + row) * D_DIM + lc * 8);
    }
#pragma unroll
    for (int q = 0; q < 4; ++q) {
      int j = wave * 256 + q * 64 + lane;
      int row = j >> 3, sc = j & 7;           // 128 rows x 8 chunks
      int lc = sc ^ (row & 7);
      async16(&sVs[buf][(wave * 256 + q * 64) * 8],
              Xtb + (size_t)row * T_DIM + sb + lc * 8);
    }
  };

  stage(0, s_beg);

  for (int it = 0; it < NIT; ++it) {
    const int buf = it & 1;
    const int sb = s_beg + it * SBLK;

    // issue next tile, then counted wait: own prior-tile (buf) issues complete,
    // the 8 just-issued (buf^1) stay in flight across the barrier.
    if (it < NIT - 1) {
      stage(buf ^ 1, sb + SBLK);
      asm volatile("s_waitcnt vmcnt(8)" ::: "memory");
    } else {
      asm volatile("s_waitcnt vmcnt(0)" ::: "memory");
    }
    __builtin_amdgcn_sched_barrier(0);
    __builtin_amdgcn_s_barrier();        // all waves: buf fully staged

    const short* kb = &sKs[buf][0];
    const short* vb = &sVs[buf][0];

    // ---- two 32-s sub-iterations over the 64-s staged tile ----
#pragma unroll
    for (int sub = 0; sub < 2; ++sub) {
      // LDS -> reg fragments
      bf16x8 kf[8];
#pragma unroll
      for (int kc = 0; kc < 8; ++kc)
        kf[kc] = *(const bf16x8*)(kb + sub * 32 * 128 + oK[kc]);
      bf16x8 vf[4][2];
#pragma unroll
      for (int dt = 0; dt < 4; ++dt)
#pragma unroll
        for (int sck = 0; sck < 2; ++sck)
          vf[dt][sck] = *(const bf16x8*)(vb + (dt * 32 + tl) * 64 +
                                         (((sub * 4 + sck * 2 + h) ^ (tl & 7)) * 8));

      // ---- QK^T (swapped), TWO independent 4-deep chains -> merge ----
      f32x16 sa, sb2;
#pragma unroll
      for (int r = 0; r < 16; ++r) { sa[r] = 0.f; sb2[r] = 0.f; }
#pragma unroll
      for (int kc = 0; kc < 4; ++kc) {
        sa  = __builtin_amdgcn_mfma_f32_32x32x16_bf16(kf[kc],     qf[kc],     sa,  0, 0, 0);
        sb2 = __builtin_amdgcn_mfma_f32_32x32x16_bf16(kf[kc + 4], qf[kc + 4], sb2, 0, 0, 0);
      }
      f32x16 sc = sa + sb2;

      const bool isd = (sb + sub * 32 == t0w);   // wave-uniform

      // ---- per s-chunk of 16: exp2 + in-register pack -> PV (R10-verified) ----
#pragma unroll
      for (int sck = 0; sck < 2; ++sck) {
        float p[8];
#pragma unroll
        for (int q = 0; q < 8; ++q) p[q] = fexp2(sc[sck * 8 + q]);
        if (isd) {   // wave-uniform branch: only the diagonal sub-iteration
#pragma unroll
          for (int q = 0; q < 8; ++q) {
            int rowid = (q & 3) + 8 * (q >> 2) + 16 * sck + 4 * h;  // s_local
            if (rowid == tl) p[q] *= expCtr;
          }
        }
#pragma unroll
        for (int q = 0; q < 8; ++q) denacc += p[q];
        unsigned int W0 = cvt_pk_bf16(p[0], p[1]);
        unsigned int W1 = cvt_pk_bf16(p[2], p[3]);
        unsigned int W2 = cvt_pk_bf16(p[4], p[5]);
        unsigned int W3 = cvt_pk_bf16(p[6], p[7]);
        permswap(W0, W2);
        permswap(W1, W3);
        union PU { unsigned int wd[4]; bf16x8 v; } pu;
        pu.wd[0] = W0; pu.wd[1] = W1; pu.wd[2] = W2; pu.wd[3] = W3;
#pragma unroll
        for (int dt = 0; dt < 4; ++dt)
          acc[dt] = __builtin_amdgcn_mfma_f32_32x32x16_bf16(pu.v, vf[dt][sck],
                                                            acc[dt], 0, 0, 0);
      }
    }

    // all waves done reading buf before anyone re-stages it next iteration
    __builtin_amdgcn_s_barrier();
  }

  // ---- den: own half + other half (same t, lane^32) ----
  float den = denacc + __shfl_xor(denacc, 32);
  if (lane < 32)
    rsp[(b * NS + ns) * T_DIM + t0w + lane] = den;

  // ---- write num partials (bf16), 32x32 C/D layout (R10-verified) ----
  const size_t pbase = ((size_t)(b * NS + ns)) * T_DIM * D_DIM;
#pragma unroll
  for (int dt = 0; dt < 4; ++dt)
#pragma unroll
    for (int r = 0; r < 16; ++r) {
      int rowid = (r & 3) + 8 * (r >> 2) + 4 * h;   // t_local
      accp[pbase + (size_t)(t0w + rowid) * D_DIM + dt * 32 + tl] =
          (unsigned short)cvt_pk_bf16(acc[dt][r], 0.f);
    }
}

// ---------------- Kernel D: combine split-K partials, 8 elems/thread, b128 ----------------
// XCD swizzle: bid&7 == b so accp/rsp reads hit the XCD-local L2.
__global__ void __launch_bounds__(256) k_comb(
    const unsigned short* __restrict__ accp, const float* __restrict__ rsp,
    float* __restrict__ out) {
  const int lin = blockIdx.x;
  const int b = lin & 7;
  const int kk = lin >> 3;                      // 0..127
  int ib = kk * 2048 + threadIdx.x * 8;         // element base within batch
  int d = ib & 127;
  int t = ib >> 7;
  float num[8] = {0.f, 0.f, 0.f, 0.f, 0.f, 0.f, 0.f, 0.f};
  float den = 0.f;
#pragma unroll
  for (int ns = 0; ns < NS; ++ns) {
    const unsigned short* p =
        accp + (((size_t)(b * NS + ns)) * T_DIM + t) * D_DIM + d;
    bf16x8 v = *(const bf16x8*)p;
#pragma unroll
    for (int j = 0; j < 8; ++j) num[j] += bf2f((unsigned short)v[j]);
    den += rsp[(b * NS + ns) * T_DIM + t];
  }
  float inv = 1.0f / den;
  float* o = out + ((size_t)b * T_DIM * D_DIM + ib);
  f32x4 o0 = (f32x4){num[0] * inv, num[1] * inv, num[2] * inv, num[3] * inv};
  f32x4 o1 = (f32x4){num[4] * inv, num[5] * inv, num[6] * inv, num[7] * inv};
  *(f32x4*)(o + 0) = o0;
  *(f32x4*)(o + 4) = o1;
}

extern "C" void kernel_launch(void* const* d_in, const int* in_sizes, int n_in,
                              void* d_out, int out_size, void* d_ws, size_t ws_size,
                              hipStream_t stream) {
  const float* X = (const float*)d_in[0];  // (8, 2048, 128) fp32
  const float* W = (const float*)d_in[1];  // (128, 64) fp32
  float* out = (float*)d_out;
  char* ws = (char*)d_ws;

  unsigned short* Sb = (unsigned short*)(ws);                 // 32 KB bf16 (frag layout)
  float* part        = (float*)(ws + 32768);                  // 2 KB
  unsigned short* Qb = (unsigned short*)(ws + 65536);         // 4 MB bf16 (frag layout)
  unsigned short* Xb = (unsigned short*)(ws + 65536 + 4194304);              // 4 MB
  unsigned short* Xt = (unsigned short*)(ws + 65536 + 2 * 4194304);          // 4 MB
  unsigned short* accp = (unsigned short*)(ws + 65536 + 3 * 4194304);        // 16 MB
  float* rsp         = (float*)(ws + 65536 + 3 * 4194304 + 16777216);        // 256 KB
  // total ws use: ~28.9 MB

  k_s<<<64, 256, 0, stream>>>(W, Sb);
  k_prep<<<dim3(T_DIM / 32, B_DIM), 128, 0, stream>>>(X, Sb, Qb, Xb, Xt, part);
  k_attn<<<(T_DIM / 128) * NS * B_DIM, 256, 0, stream>>>(Qb, Xb, Xt, part, accp, rsp);
  k_comb<<<B_DIM * 128, 256, 0, stream>>>(accp, rsp, out);
}

// Round 21
// 43.540 us; speedup vs baseline: 1.0727x; 1.0045x over previous
//
#include <hip/hip_runtime.h>
#include <hip/hip_bf16.h>
#include <math.h>

#define D_DIM 128
#define R_DIM 64
#define T_DIM 2048
#define B_DIM 8
#define NS 4                       // split-K factor over the s dimension
#define SCHUNK (T_DIM / NS)        // 512
#define SBLK 64                    // s-tile per staged iteration (R20-proven)
#define NIT (SCHUNK / SBLK)        // 8
#define KE_CONST (0.08838834764831845f * 1.4426950408889634f)  // 1/sqrt(128) * log2(e)

typedef __attribute__((ext_vector_type(8))) short bf16x8;
typedef __attribute__((ext_vector_type(4))) short s16x4;
typedef __attribute__((ext_vector_type(4))) float f32x4;
typedef __attribute__((ext_vector_type(16))) float f32x16;

__device__ inline unsigned short f2bf(float f) {
  union { float f; unsigned int u; } v; v.f = f;
  return (unsigned short)((v.u + 0x7FFFu + ((v.u >> 16) & 1u)) >> 16);
}
__device__ inline float bf2f(unsigned short u) {
  union { unsigned int u; float f; } v; v.u = ((unsigned int)u) << 16;
  return v.f;
}
// packed RNE f32->bf16 pair: low half = lo, high half = hi (T12 recipe)
__device__ inline unsigned int cvt_pk_bf16(float lo, float hi) {
  unsigned int r;
  asm("v_cvt_pk_bf16_f32 %0, %1, %2" : "=v"(r) : "v"(lo), "v"(hi));
  return r;
}
// v_permlane32_swap_b32: lane l<32: a'=a, b'=a[l+32]; lane l>=32: a'=b[l-32], b'=b.
__device__ inline void permswap(unsigned int& a, unsigned int& b) {
  asm("v_permlane32_swap_b32 %0, %1" : "+v"(a), "+v"(b));
}
// raw 2^x (input |x| small -> no libm edge handling needed)
__device__ inline float fexp2(float x) {
  float r;
  asm("v_exp_f32 %0, %1" : "=v"(r) : "v"(x));
  return r;
}

// async global->LDS, 16B per lane; LDS dest = wave-uniform base + lane*16
__device__ inline void async16(const short* l, const unsigned short* g) {
  __builtin_amdgcn_global_load_lds(
      (const __attribute__((address_space(1))) unsigned int*)g,
      (__attribute__((address_space(3))) unsigned int*)l, 16, 0, 0);
}

// ---------------- Kernel A: S = W W^T / sqrt(D*R), bf16, FRAGMENT layout ----------------
// Layout matches k_prep's B-frag read: Sb[((dc*4+kc)*64 + lane)*8 + j] with
// lane = g*16+c holding S[dc*16+c][kc*32+g*8+j].  (R12-verified)
__global__ void k_s(const float* __restrict__ W, unsigned short* __restrict__ Sb) {
  int gid = blockIdx.x * 256 + threadIdx.x;
  int i = gid >> 7, j = gid & 127;
  const float* wi = W + i * R_DIM;
  const float* wj = W + j * R_DIM;
  float acc = 0.f;
#pragma unroll 8
  for (int r = 0; r < R_DIM; ++r) acc += wi[r] * wj[r];
  int off = (((i >> 4) * 4 + (j >> 5)) * 64 + ((j & 31) >> 3) * 16 + (i & 15)) * 8 + (j & 7);
  Sb[off] = f2bf(acc * 0.011048543456039806f);  // 1/sqrt(128*64)
}

// ---------------- Kernel B: MFMA Q = X*S, K-SPLIT over 2 waves (R21) ----------------
// 16 t-rows/block, grid 1024 -> 8 waves/CU (was 4). Wave w computes partial Q
// over kc in {2w, 2w+1} (loads only its X column-half -> same HBM traffic);
// wave 1 parks partials in LDS; wave 0 merges, computes trace + Qb (frag
// layout, R12-verified). Xt flushed by both waves from xbT[128][16].
__global__ void __launch_bounds__(128) k_prep(
    const float* __restrict__ X, const unsigned short* __restrict__ Sb,
    unsigned short* __restrict__ Qb, unsigned short* __restrict__ Xb,
    unsigned short* __restrict__ Xt, float* __restrict__ part) {
  const int tid = threadIdx.x;
  const int w = tid >> 6, lane = tid & 63;
  const int g = lane >> 4, c = lane & 15;
  const int b = blockIdx.y;
  const int t0 = blockIdx.x * 16;       // 16 t-rows per block

  __shared__ __align__(16) short xbT[D_DIM * 16];     // [e][t-local], 4 KB
  __shared__ __align__(16) float accLds[8 * 64 * 4];  // wave-1 partials, 8 KB

  // load X half-rows (cols w*64 .. w*64+63), cvt, write Xb, fill xbT e-half
  union FU { unsigned int wd[4]; bf16x8 v; };
  bf16x8 xf[2];
#pragma unroll
  for (int kcl = 0; kcl < 2; ++kcl) {
    const int kc = w * 2 + kcl;
    const float* xp = X + ((size_t)(b * T_DIM + t0 + c)) * D_DIM + kc * 32 + g * 8;
    f32x4 a = *(const f32x4*)xp;
    f32x4 bb = *(const f32x4*)(xp + 4);
    FU f;
    f.wd[0] = cvt_pk_bf16(a[0], a[1]);
    f.wd[1] = cvt_pk_bf16(a[2], a[3]);
    f.wd[2] = cvt_pk_bf16(bb[0], bb[1]);
    f.wd[3] = cvt_pk_bf16(bb[2], bb[3]);
    xf[kcl] = f.v;
    *(bf16x8*)(Xb + ((size_t)(b * T_DIM + t0 + c)) * D_DIM + kc * 32 + g * 8) = f.v;
#pragma unroll
    for (int jw = 0; jw < 4; ++jw) {
      unsigned int wv = f.wd[jw];
      int e = kc * 32 + g * 8 + jw * 2;
      xbT[(e + 0) * 16 + c] = (short)wv;
      xbT[(e + 1) * 16 + c] = (short)(wv >> 16);
    }
  }

  // partial MFMA: acc[dc] = X(16 rows, this wave's K-half) * S-half
  f32x4 acc[8];
#pragma unroll
  for (int dc = 0; dc < 8; ++dc) acc[dc] = (f32x4){0.f, 0.f, 0.f, 0.f};
#pragma unroll
  for (int dc = 0; dc < 8; ++dc) {
    bf16x8 sf[2];
#pragma unroll
    for (int kcl = 0; kcl < 2; ++kcl)
      sf[kcl] = *(const bf16x8*)(Sb + ((size_t)(dc * 4 + w * 2 + kcl) * 64 + lane) * 8);
#pragma unroll
    for (int kcl = 0; kcl < 2; ++kcl)
      acc[dc] = __builtin_amdgcn_mfma_f32_16x16x32_bf16(xf[kcl], sf[kcl], acc[dc], 0, 0, 0);
  }

  // wave 1 parks partials (C/D layout identical across waves)
  if (w == 1) {
#pragma unroll
    for (int dc = 0; dc < 8; ++dc)
#pragma unroll
      for (int r = 0; r < 4; ++r)
        accLds[dc * 256 + lane * 4 + r] = acc[dc][r];
  }
  __syncthreads();   // xbT (both halves) + accLds complete

  if (w == 0) {
    // merge + trace + Qb (frag layout)
    float trp = 0.f;
#pragma unroll
    for (int dc = 0; dc < 8; ++dc)
#pragma unroll
      for (int r = 0; r < 4; ++r) {
        float q = acc[dc][r] + accLds[dc * 256 + lane * 4 + r];
        float x = bf2f((unsigned short)xbT[(dc * 16 + c) * 16 + g * 4 + r]);
        trp += q * x;
        int t = t0 + g * 4 + r;
        size_t qoff = (((size_t)(b * 64 + (t >> 5)) * 8 + dc) * 512 +
                       ((c >> 3) * 32 + (t & 31)) * 8 + (c & 7));
        Qb[qoff] = (unsigned short)cvt_pk_bf16(q * KE_CONST, 0.f);
      }
    // wave-reduce trace partial
    trp += __shfl_xor(trp, 1); trp += __shfl_xor(trp, 2);
    trp += __shfl_xor(trp, 4); trp += __shfl_xor(trp, 8);
    trp += __shfl_xor(trp, 16); trp += __shfl_xor(trp, 32);
    if (lane == 0) part[b * 128 + blockIdx.x] = trp;
  }

  // write Xt from xbT: 2 chunks/thread, b128 in / b128 out (both waves)
#pragma unroll
  for (int p = 0; p < 2; ++p) {
    int row = p * 64 + (tid >> 1);
    bf16x8 v = *(const bf16x8*)&xbT[row * 16 + (tid & 1) * 8];
    *(bf16x8*)(Xt + ((size_t)(b * D_DIM + row)) * T_DIM + t0 + (tid & 1) * 8) = v;
  }
}

// ---------------- Kernel C: flash attention — R20 (best known); part has 128 entries ----------------
__global__ void __launch_bounds__(256, 2) k_attn(
    const unsigned short* __restrict__ Qb, const unsigned short* __restrict__ Xb,
    const unsigned short* __restrict__ Xt, const float* __restrict__ part,
    unsigned short* __restrict__ accp, float* __restrict__ rsp) {
  const int tid = threadIdx.x;
  const int wave = tid >> 6, lane = tid & 63;
  const int tl = lane & 31;      // C/D col = t-local; A row = s-local
  const int h = lane >> 5;       // half-wave -> k_local*8
  // XCD-aware decomposition: bid&7 == b pins batch b's working set to one XCD.
  const int lin = blockIdx.x;
  const int b = lin & 7;
  const int kk = lin >> 3;
  const int ns = kk & 3;
  const int tile = kk >> 2;                      // 0..15
  const int t0w = tile * 128 + wave * 32;        // 32 q-rows per wave

  const unsigned short* Xbb = Xb + (size_t)b * T_DIM * D_DIM;
  const unsigned short* Xtb = Xt + (size_t)b * D_DIM * T_DIM;

  // inline trace reduction (per-wave redundant, L2-hot; 128 partials now)
  float tv = part[b * 128 + lane] + part[b * 128 + 64 + lane];
  tv += __shfl_xor(tv, 1); tv += __shfl_xor(tv, 2);
  tv += __shfl_xor(tv, 4); tv += __shfl_xor(tv, 8);
  tv += __shfl_xor(tv, 16); tv += __shfl_xor(tv, 32);
  const float ctrK = tv * (1.0f / T_DIM) * KE_CONST;
  const float expCtr = fexp2(-ctrK);   // diag correction as multiplier

  __shared__ __align__(16) short sKs[2][SBLK * D_DIM];   // 2 x 16 KB
  __shared__ __align__(16) short sVs[2][D_DIM * SBLK];   // 2 x 16 KB

  // swizzled ds_read offsets (shorts)
  int oK[8];                    // K: row tl (+sub*32 added at use), 16-slot XOR
#pragma unroll
  for (int kc = 0; kc < 8; ++kc)
    oK[kc] = tl * 128 + (((kc * 2 + h) ^ (tl & 15)) * 8);
  // V: [128][64] rows, chunk index (sub*4 + sck*2 + h) ^ (tl&7), 8-slot XOR

  // Q B-frags, COALESCED from frag-layout Qb (R12-verified layout)
  const unsigned short* qbase =
      Qb + ((size_t)(b * 64 + tile * 4 + wave)) * 8 * 512;
  bf16x8 qf[8];
#pragma unroll
  for (int kc = 0; kc < 8; ++kc)
    qf[kc] = *(const bf16x8*)(qbase + (size_t)kc * 512 + lane * 8);

  f32x16 acc[4];
#pragma unroll
  for (int dt = 0; dt < 4; ++dt)
#pragma unroll
    for (int r = 0; r < 16; ++r) acc[dt][r] = 0.f;
  float denacc = 0.f;

  const int s_beg = ns * SCHUNK;

  // staging: K 1024 chunks + V 1024 chunks over 4 waves (4+4 issues/lane = 8 vmem)
  auto stage = [&](int buf, int sb) {
#pragma unroll
    for (int q = 0; q < 4; ++q) {
      int j = wave * 256 + q * 64 + lane;
      int row = j >> 4, sc = j & 15;          // 64 rows x 16 chunks
      int lc = sc ^ (row & 15);
      async16(&sKs[buf][(wave * 256 + q * 64) * 8],
              Xbb + (size_t)(sb + row) * D_DIM + lc * 8);
    }
#pragma unroll
    for (int q = 0; q < 4; ++q) {
      int j = wave * 256 + q * 64 + lane;
      int row = j >> 3, sc = j & 7;           // 128 rows x 8 chunks
      int lc = sc ^ (row & 7);
      async16(&sVs[buf][(wave * 256 + q * 64) * 8],
              Xtb + (size_t)row * T_DIM + sb + lc * 8);
    }
  };

  stage(0, s_beg);

  for (int it = 0; it < NIT; ++it) {
    const int buf = it & 1;
    const int sb = s_beg + it * SBLK;

    // issue next tile, then counted wait: own prior-tile (buf) issues complete,
    // the 8 just-issued (buf^1) stay in flight across the barrier.
    if (it < NIT - 1) {
      stage(buf ^ 1, sb + SBLK);
      asm volatile("s_waitcnt vmcnt(8)" ::: "memory");
    } else {
      asm volatile("s_waitcnt vmcnt(0)" ::: "memory");
    }
    __builtin_amdgcn_sched_barrier(0);
    __builtin_amdgcn_s_barrier();        // all waves: buf fully staged

    const short* kb = &sKs[buf][0];
    const short* vb = &sVs[buf][0];

    // ---- two 32-s sub-iterations over the 64-s staged tile ----
#pragma unroll
    for (int sub = 0; sub < 2; ++sub) {
      // LDS -> reg fragments
      bf16x8 kf[8];
#pragma unroll
      for (int kc = 0; kc < 8; ++kc)
        kf[kc] = *(const bf16x8*)(kb + sub * 32 * 128 + oK[kc]);
      bf16x8 vf[4][2];
#pragma unroll
      for (int dt = 0; dt < 4; ++dt)
#pragma unroll
        for (int sck = 0; sck < 2; ++sck)
          vf[dt][sck] = *(const bf16x8*)(vb + (dt * 32 + tl) * 64 +
                                         (((sub * 4 + sck * 2 + h) ^ (tl & 7)) * 8));

      // ---- QK^T (swapped), TWO independent 4-deep chains -> merge ----
      f32x16 sa, sb2;
#pragma unroll
      for (int r = 0; r < 16; ++r) { sa[r] = 0.f; sb2[r] = 0.f; }
#pragma unroll
      for (int kc = 0; kc < 4; ++kc) {
        sa  = __builtin_amdgcn_mfma_f32_32x32x16_bf16(kf[kc],     qf[kc],     sa,  0, 0, 0);
        sb2 = __builtin_amdgcn_mfma_f32_32x32x16_bf16(kf[kc + 4], qf[kc + 4], sb2, 0, 0, 0);
      }
      f32x16 sc = sa + sb2;

      const bool isd = (sb + sub * 32 == t0w);   // wave-uniform

      // ---- per s-chunk of 16: exp2 + in-register pack -> PV (R10-verified) ----
#pragma unroll
      for (int sck = 0; sck < 2; ++sck) {
        float p[8];
#pragma unroll
        for (int q = 0; q < 8; ++q) p[q] = fexp2(sc[sck * 8 + q]);
        if (isd) {   // wave-uniform branch: only the diagonal sub-iteration
#pragma unroll
          for (int q = 0; q < 8; ++q) {
            int rowid = (q & 3) + 8 * (q >> 2) + 16 * sck + 4 * h;  // s_local
            if (rowid == tl) p[q] *= expCtr;
          }
        }
#pragma unroll
        for (int q = 0; q < 8; ++q) denacc += p[q];
        unsigned int W0 = cvt_pk_bf16(p[0], p[1]);
        unsigned int W1 = cvt_pk_bf16(p[2], p[3]);
        unsigned int W2 = cvt_pk_bf16(p[4], p[5]);
        unsigned int W3 = cvt_pk_bf16(p[6], p[7]);
        permswap(W0, W2);
        permswap(W1, W3);
        union PU { unsigned int wd[4]; bf16x8 v; } pu;
        pu.wd[0] = W0; pu.wd[1] = W1; pu.wd[2] = W2; pu.wd[3] = W3;
#pragma unroll
        for (int dt = 0; dt < 4; ++dt)
          acc[dt] = __builtin_amdgcn_mfma_f32_32x32x16_bf16(pu.v, vf[dt][sck],
                                                            acc[dt], 0, 0, 0);
      }
    }

    // all waves done reading buf before anyone re-stages it next iteration
    __builtin_amdgcn_s_barrier();
  }

  // ---- den: own half + other half (same t, lane^32) ----
  float den = denacc + __shfl_xor(denacc, 32);
  if (lane < 32)
    rsp[(b * NS + ns) * T_DIM + t0w + lane] = den;

  // ---- write num partials (bf16), 32x32 C/D layout (R10-verified) ----
  const size_t pbase = ((size_t)(b * NS + ns)) * T_DIM * D_DIM;
#pragma unroll
  for (int dt = 0; dt < 4; ++dt)
#pragma unroll
    for (int r = 0; r < 16; ++r) {
      int rowid = (r & 3) + 8 * (r >> 2) + 4 * h;   // t_local
      accp[pbase + (size_t)(t0w + rowid) * D_DIM + dt * 32 + tl] =
          (unsigned short)cvt_pk_bf16(acc[dt][r], 0.f);
    }
}

// ---------------- Kernel D: combine split-K partials, 8 elems/thread, b128 ----------------
// XCD swizzle: bid&7 == b so accp/rsp reads hit the XCD-local L2.
__global__ void __launch_bounds__(256) k_comb(
    const unsigned short* __restrict__ accp, const float* __restrict__ rsp,
    float* __restrict__ out) {
  const int lin = blockIdx.x;
  const int b = lin & 7;
  const int kk = lin >> 3;                      // 0..127
  int ib = kk * 2048 + threadIdx.x * 8;         // element base within batch
  int d = ib & 127;
  int t = ib >> 7;
  float num[8] = {0.f, 0.f, 0.f, 0.f, 0.f, 0.f, 0.f, 0.f};
  float den = 0.f;
#pragma unroll
  for (int ns = 0; ns < NS; ++ns) {
    const unsigned short* p =
        accp + (((size_t)(b * NS + ns)) * T_DIM + t) * D_DIM + d;
    bf16x8 v = *(const bf16x8*)p;
#pragma unroll
    for (int j = 0; j < 8; ++j) num[j] += bf2f((unsigned short)v[j]);
    den += rsp[(b * NS + ns) * T_DIM + t];
  }
  float inv = 1.0f / den;
  float* o = out + ((size_t)b * T_DIM * D_DIM + ib);
  f32x4 o0 = (f32x4){num[0] * inv, num[1] * inv, num[2] * inv, num[3] * inv};
  f32x4 o1 = (f32x4){num[4] * inv, num[5] * inv, num[6] * inv, num[7] * inv};
  *(f32x4*)(o + 0) = o0;
  *(f32x4*)(o + 4) = o1;
}

extern "C" void kernel_launch(void* const* d_in, const int* in_sizes, int n_in,
                              void* d_out, int out_size, void* d_ws, size_t ws_size,
                              hipStream_t stream) {
  const float* X = (const float*)d_in[0];  // (8, 2048, 128) fp32
  const float* W = (const float*)d_in[1];  // (128, 64) fp32
  float* out = (float*)d_out;
  char* ws = (char*)d_ws;

  unsigned short* Sb = (unsigned short*)(ws);                 // 32 KB bf16 (frag layout)
  float* part        = (float*)(ws + 32768);                  // 4 KB (128/batch now)
  unsigned short* Qb = (unsigned short*)(ws + 65536);         // 4 MB bf16 (frag layout)
  unsigned short* Xb = (unsigned short*)(ws + 65536 + 4194304);              // 4 MB
  unsigned short* Xt = (unsigned short*)(ws + 65536 + 2 * 4194304);          // 4 MB
  unsigned short* accp = (unsigned short*)(ws + 65536 + 3 * 4194304);        // 16 MB
  float* rsp         = (float*)(ws + 65536 + 3 * 4194304 + 16777216);        // 256 KB
  // total ws use: ~28.9 MB

  k_s<<<64, 256, 0, stream>>>(W, Sb);
  k_prep<<<dim3(T_DIM / 16, B_DIM), 128, 0, stream>>>(X, Sb, Qb, Xb, Xt, part);
  k_attn<<<(T_DIM / 128) * NS * B_DIM, 256, 0, stream>>>(Qb, Xb, Xt, part, accp, rsp);
  k_comb<<<B_DIM * 128, 256, 0, stream>>>(accp, rsp, out);
}